// Round 1
// baseline (237.275 us; speedup 1.0000x reference)
//
#include <hip/hip_runtime.h>
#include <hip/hip_bf16.h>
#include <cstddef>
#include <cstdint>

typedef __attribute__((ext_vector_type(8))) short bf16x8;
typedef __attribute__((ext_vector_type(4))) float f32x4;

#define MFMA16(a, b, c) __builtin_amdgcn_mfma_f32_16x16x32_bf16((a), (b), (c), 0, 0, 0)

static constexpr int B = 4, S = 512, HID = 768, NH = 12, HD = 64;
static constexpr int QKV_N = B * NH * S * HD;            // 1,572,864 floats per matrix
static constexpr size_t SCORES_N = (size_t)B * NH * S * S; // 12,582,912 floats

// f32 -> bf16 round-to-nearest-even (inputs finite)
__device__ __forceinline__ short f2bf(float f) {
  unsigned u = __builtin_bit_cast(unsigned, f);
  u += 0x7FFFu + ((u >> 16) & 1u);
  return (short)(u >> 16);
}

// load 8 consecutive f32 (32B-aligned) and convert to a bf16x8 MFMA fragment
__device__ __forceinline__ bf16x8 ld_cvt8(const float* __restrict__ p) {
  float4 a = *reinterpret_cast<const float4*>(p);
  float4 b = *reinterpret_cast<const float4*>(p + 4);
  bf16x8 r;
  r[0] = f2bf(a.x); r[1] = f2bf(a.y); r[2] = f2bf(a.z); r[3] = f2bf(a.w);
  r[4] = f2bf(b.x); r[5] = f2bf(b.y); r[6] = f2bf(b.z); r[7] = f2bf(b.w);
  return r;
}

// ---------------------------------------------------------------------------
// K1: fused QKV projection.  out[mat][b][h][i][d] = x[b,i,:] @ W[:,n] + bias
// M=2048 (b*512+i), K=768, N = 3*768. 64x64 tiles, BK=32, 4 waves (2x2 of 32x32).
// ---------------------------------------------------------------------------
__global__ __launch_bounds__(256) void k_qkv(
    const float* __restrict__ x,
    const float* __restrict__ Wq, const float* __restrict__ bq,
    const float* __restrict__ Wk, const float* __restrict__ bk,
    const float* __restrict__ Wv, const float* __restrict__ bv,
    float* __restrict__ qkv) {
  __shared__ short As[64 * 40];  // [row m][k] bf16, pad 32->40 to spread banks
  __shared__ short Bs[64 * 40];  // [col n][k] bf16 (W transposed), same pad
  const int m0 = blockIdx.x * 64;
  const int nt = blockIdx.y;          // 0..35
  const int mat = nt / 12;
  const int nc0 = (nt % 12) * 64;
  const float* __restrict__ W    = (mat == 0) ? Wq : (mat == 1) ? Wk : Wv;
  const float* __restrict__ bias = (mat == 0) ? bq : (mat == 1) ? bk : bv;
  float* __restrict__ outp = qkv + (size_t)mat * QKV_N;
  const int t = threadIdx.x;
  const int w = t >> 6, lane = t & 63;
  const int wm = (w >> 1) * 32, wn = (w & 1) * 32;
  const int lr = lane & 15, lk = lane >> 4;
  f32x4 acc[2][2] = {};
  for (int kk = 0; kk < 768; kk += 32) {
#pragma unroll
    for (int it = 0; it < 2; ++it) {
      int f = it * 256 + t;
      {  // stage A tile: 64 rows x 32 k
        int r = f >> 3, c4 = f & 7;
        float4 v = *reinterpret_cast<const float4*>(x + (size_t)(m0 + r) * 768 + kk + c4 * 4);
        short* d = &As[r * 40 + c4 * 4];
        d[0] = f2bf(v.x); d[1] = f2bf(v.y); d[2] = f2bf(v.z); d[3] = f2bf(v.w);
      }
      {  // stage B tile transposed: W[k][n] -> Bs[n][k]
        int kr = f >> 4, c4 = f & 15;
        float4 v = *reinterpret_cast<const float4*>(W + (size_t)(kk + kr) * 768 + nc0 + c4 * 4);
        int c = c4 * 4;
        Bs[(c + 0) * 40 + kr] = f2bf(v.x);
        Bs[(c + 1) * 40 + kr] = f2bf(v.y);
        Bs[(c + 2) * 40 + kr] = f2bf(v.z);
        Bs[(c + 3) * 40 + kr] = f2bf(v.w);
      }
    }
    __syncthreads();
    bf16x8 a0 = *reinterpret_cast<const bf16x8*>(&As[(wm + lr) * 40 + lk * 8]);
    bf16x8 a1 = *reinterpret_cast<const bf16x8*>(&As[(wm + 16 + lr) * 40 + lk * 8]);
    bf16x8 b0 = *reinterpret_cast<const bf16x8*>(&Bs[(wn + lr) * 40 + lk * 8]);
    bf16x8 b1 = *reinterpret_cast<const bf16x8*>(&Bs[(wn + 16 + lr) * 40 + lk * 8]);
    acc[0][0] = MFMA16(a0, b0, acc[0][0]);
    acc[0][1] = MFMA16(a0, b1, acc[0][1]);
    acc[1][0] = MFMA16(a1, b0, acc[1][0]);
    acc[1][1] = MFMA16(a1, b1, acc[1][1]);
    __syncthreads();
  }
#pragma unroll
  for (int mf = 0; mf < 2; ++mf)
#pragma unroll
    for (int nf = 0; nf < 2; ++nf) {
      int col = nc0 + wn + nf * 16 + lr;  // 0..767 within this matrix
      float bv_ = bias[col];
      int h = col >> 6, d = col & 63;
#pragma unroll
      for (int reg = 0; reg < 4; ++reg) {
        int m = m0 + wm + mf * 16 + lk * 4 + reg;
        int b_ = m >> 9, i = m & 511;
        outp[(size_t)((b_ * NH + h) * S + i) * HD + d] = acc[mf][nf][reg] + bv_;
      }
    }
}

// ---------------------------------------------------------------------------
// K2: qr[b,h,i,r] = 0.125 * sum_d q[b,h,i,d] * Wr[r,d]   (scale folded in)
// Per (b,h): (512 x 64) @ Wr^T(64 x 64). Direct-from-global fragments, K=64.
// ---------------------------------------------------------------------------
__global__ __launch_bounds__(256) void k_qr(const float* __restrict__ q,
                                            const float* __restrict__ Wr,
                                            float* __restrict__ qr) {
  const int i0 = blockIdx.x * 64;
  const int h = blockIdx.y, b = blockIdx.z;
  const float* __restrict__ qp = q + (size_t)((b * NH + h) * S) * HD;
  float* __restrict__ op = qr + (size_t)((b * NH + h) * S) * HD;
  const int t = threadIdx.x;
  const int w = t >> 6, lane = t & 63;
  const int wm = (w >> 1) * 32, wn = (w & 1) * 32;
  const int lr = lane & 15, lk = lane >> 4;
  f32x4 acc[2][2] = {};
#pragma unroll
  for (int ks = 0; ks < 2; ++ks) {
    int k0 = ks * 32 + lk * 8;
    bf16x8 a0 = ld_cvt8(qp + (size_t)(i0 + wm + lr) * 64 + k0);
    bf16x8 a1 = ld_cvt8(qp + (size_t)(i0 + wm + 16 + lr) * 64 + k0);
    bf16x8 b0 = ld_cvt8(Wr + (size_t)(wn + lr) * 64 + k0);
    bf16x8 b1 = ld_cvt8(Wr + (size_t)(wn + 16 + lr) * 64 + k0);
    acc[0][0] = MFMA16(a0, b0, acc[0][0]);
    acc[0][1] = MFMA16(a0, b1, acc[0][1]);
    acc[1][0] = MFMA16(a1, b0, acc[1][0]);
    acc[1][1] = MFMA16(a1, b1, acc[1][1]);
  }
#pragma unroll
  for (int mf = 0; mf < 2; ++mf)
#pragma unroll
    for (int nf = 0; nf < 2; ++nf) {
      int r = wn + nf * 16 + lr;
#pragma unroll
      for (int reg = 0; reg < 4; ++reg) {
        int i = i0 + wm + mf * 16 + lk * 4 + reg;
        op[(size_t)i * 64 + r] = acc[mf][nf][reg] * 0.125f;
      }
    }
}

// ---------------------------------------------------------------------------
// K3a: scores[b,h,i,j] = 0.125 * q.k  + (1 - graph - end) * (-1e9)
// Per (b,h): M=512(i) x N=512(j), K=64. 64x64 tiles, direct global frags.
// ---------------------------------------------------------------------------
__global__ __launch_bounds__(256) void k_qk(const float* __restrict__ q,
                                            const float* __restrict__ kmat,
                                            const float* __restrict__ graph,
                                            const float* __restrict__ endm,
                                            float* __restrict__ scores) {
  const int j0 = blockIdx.x * 64, i0 = blockIdx.y * 64;
  const int bh = blockIdx.z;  // 0..47
  const int b = bh / NH;
  const float* __restrict__ qp = q + (size_t)(bh * S) * HD;
  const float* __restrict__ kp = kmat + (size_t)(bh * S) * HD;
  const int t = threadIdx.x;
  const int w = t >> 6, lane = t & 63;
  const int wm = (w >> 1) * 32, wn = (w & 1) * 32;
  const int lr = lane & 15, lk = lane >> 4;
  f32x4 acc[2][2] = {};
#pragma unroll
  for (int ks = 0; ks < 2; ++ks) {
    int k0 = ks * 32 + lk * 8;
    bf16x8 a0 = ld_cvt8(qp + (size_t)(i0 + wm + lr) * 64 + k0);
    bf16x8 a1 = ld_cvt8(qp + (size_t)(i0 + wm + 16 + lr) * 64 + k0);
    bf16x8 b0 = ld_cvt8(kp + (size_t)(j0 + wn + lr) * 64 + k0);
    bf16x8 b1 = ld_cvt8(kp + (size_t)(j0 + wn + 16 + lr) * 64 + k0);
    acc[0][0] = MFMA16(a0, b0, acc[0][0]);
    acc[0][1] = MFMA16(a0, b1, acc[0][1]);
    acc[1][0] = MFMA16(a1, b0, acc[1][0]);
    acc[1][1] = MFMA16(a1, b1, acc[1][1]);
  }
#pragma unroll
  for (int mf = 0; mf < 2; ++mf)
#pragma unroll
    for (int nf = 0; nf < 2; ++nf) {
      int j = j0 + wn + nf * 16 + lr;
      float e = endm[b * S + j];
#pragma unroll
      for (int reg = 0; reg < 4; ++reg) {
        int i = i0 + wm + mf * 16 + lk * 4 + reg;
        float g = graph[(size_t)(b * S + i) * S + j];
        scores[((size_t)bh * S + i) * S + j] =
            acc[mf][nf][reg] * 0.125f + (1.0f - g - e) * (-1e9f);
      }
    }
}

// ---------------------------------------------------------------------------
// K3b: scores[b,h,i,j] += qr[b,h,i,:] . rel[b,i,j,:]  (qr already scaled)
// Per (b,i): M=16 (heads, 12 used) x N=512(j), K=64. One wave per (b,i,j-half).
// This kernel streams the 268 MB rel tensor exactly once -> HBM-bound.
// ---------------------------------------------------------------------------
__global__ __launch_bounds__(256) void k_rel(const float* __restrict__ qr,
                                             const float* __restrict__ rel,
                                             float* __restrict__ scores) {
  const int t = threadIdx.x;
  const int w = t >> 6, lane = t & 63;
  const int lr = lane & 15, fq = lane >> 4;
  const int i = blockIdx.x * 2 + (w >> 1);
  const int b = blockIdx.y;
  const int jh = w & 1;
  const int hh = lr < NH ? lr : NH - 1;  // clamp pad rows (outputs discarded)
  const float* __restrict__ qrow = qr + (size_t)((b * NH + hh) * S + i) * HD;
  bf16x8 a0 = ld_cvt8(qrow + fq * 8);
  bf16x8 a1 = ld_cvt8(qrow + 32 + fq * 8);
  const float* __restrict__ rp = rel + (size_t)(b * S + i) * S * 64;
  for (int jt = jh * 16; jt < jh * 16 + 16; ++jt) {
    int j0 = jt * 16;
    const float* __restrict__ rrow = rp + (size_t)(j0 + lr) * 64 + fq * 8;
    bf16x8 b0 = ld_cvt8(rrow);
    bf16x8 b1 = ld_cvt8(rrow + 32);
    f32x4 acc = {};
    acc = MFMA16(a0, b0, acc);
    acc = MFMA16(a1, b1, acc);
#pragma unroll
    for (int reg = 0; reg < 4; ++reg) {
      int h = fq * 4 + reg;
      if (h < NH) {
        size_t idx = ((size_t)(b * NH + h) * S + i) * S + j0 + lr;
        scores[idx] += acc[reg];
      }
    }
  }
}

// ---------------------------------------------------------------------------
// K4: in-place row softmax over j (512). One wave per (b,h,i) row.
// ---------------------------------------------------------------------------
__global__ __launch_bounds__(64) void k_softmax(float* __restrict__ scores) {
  const size_t row = blockIdx.x;
  const int lane = threadIdx.x;
  float* __restrict__ p = scores + row * S;
  float4 v0 = *reinterpret_cast<const float4*>(p + lane * 4);
  float4 v1 = *reinterpret_cast<const float4*>(p + 256 + lane * 4);
  float m = fmaxf(fmaxf(fmaxf(v0.x, v0.y), fmaxf(v0.z, v0.w)),
                  fmaxf(fmaxf(v1.x, v1.y), fmaxf(v1.z, v1.w)));
#pragma unroll
  for (int off = 32; off; off >>= 1) m = fmaxf(m, __shfl_xor(m, off));
  v0.x = __expf(v0.x - m); v0.y = __expf(v0.y - m);
  v0.z = __expf(v0.z - m); v0.w = __expf(v0.w - m);
  v1.x = __expf(v1.x - m); v1.y = __expf(v1.y - m);
  v1.z = __expf(v1.z - m); v1.w = __expf(v1.w - m);
  float s = v0.x + v0.y + v0.z + v0.w + v1.x + v1.y + v1.z + v1.w;
#pragma unroll
  for (int off = 32; off; off >>= 1) s += __shfl_xor(s, off);
  float inv = 1.0f / s;
  v0.x *= inv; v0.y *= inv; v0.z *= inv; v0.w *= inv;
  v1.x *= inv; v1.y *= inv; v1.z *= inv; v1.w *= inv;
  *reinterpret_cast<float4*>(p + lane * 4) = v0;
  *reinterpret_cast<float4*>(p + 256 + lane * 4) = v1;
}

// ---------------------------------------------------------------------------
// K5: ctx[b,i,h*64+d] = sum_j probs[b,h,i,j] * v[b,h,j,d]
// Block per (b,h, i-tile of 32). LDS-tiled over j (64 at a time).
// ---------------------------------------------------------------------------
__global__ __launch_bounds__(256) void k_pv(const float* __restrict__ scores,
                                            const float* __restrict__ v,
                                            float* __restrict__ out) {
  __shared__ float vs[64 * 64];   // [j][d]
  __shared__ float ps[32 * 68];   // [i][j], stride 68 -> conflict-free + 16B aligned
  const int i0 = blockIdx.x * 32;
  const int h = blockIdx.y, b = blockIdx.z;
  const int t = threadIdx.x;
  const int il = t >> 3, dg = t & 7;
  const float* __restrict__ vp = v + (size_t)((b * NH + h) * S) * HD;
  const float* __restrict__ pp = scores + ((size_t)(b * NH + h) * S + i0) * S;
  float acc[8] = {};
  for (int jt = 0; jt < 8; ++jt) {
    int j0 = jt * 64;
    __syncthreads();
#pragma unroll
    for (int it = 0; it < 4; ++it) {
      int f = it * 256 + t;
      int jr = f >> 4, c4 = f & 15;
      *reinterpret_cast<float4*>(&vs[jr * 64 + c4 * 4]) =
          *reinterpret_cast<const float4*>(vp + (size_t)(j0 + jr) * 64 + c4 * 4);
    }
#pragma unroll
    for (int it = 0; it < 2; ++it) {
      int f = it * 256 + t;
      int ir = f >> 4, c4 = f & 15;
      *reinterpret_cast<float4*>(&ps[ir * 68 + c4 * 4]) =
          *reinterpret_cast<const float4*>(pp + (size_t)ir * S + j0 + c4 * 4);
    }
    __syncthreads();
#pragma unroll 8
    for (int j = 0; j < 64; ++j) {
      float pval = ps[il * 68 + j];
      const float* vrow = &vs[j * 64 + dg * 8];
#pragma unroll
      for (int u = 0; u < 8; ++u) acc[u] = fmaf(pval, vrow[u], acc[u]);
    }
  }
  float* __restrict__ op = out + ((size_t)(b * S) + i0 + il) * HID + h * 64 + dg * 8;
#pragma unroll
  for (int u = 0; u < 8; ++u) op[u] = acc[u];
}

// ---------------------------------------------------------------------------
extern "C" void kernel_launch(void* const* d_in, const int* in_sizes, int n_in,
                              void* d_out, int out_size, void* d_ws, size_t ws_size,
                              hipStream_t stream) {
  const float* x     = (const float*)d_in[0];
  const float* graph = (const float*)d_in[1];
  const float* endm  = (const float*)d_in[2];
  const float* rel   = (const float*)d_in[3];
  const float* Wq = (const float*)d_in[4];  const float* bq = (const float*)d_in[5];
  const float* Wk = (const float*)d_in[6];  const float* bk = (const float*)d_in[7];
  const float* Wv = (const float*)d_in[8];  const float* bv = (const float*)d_in[9];
  const float* Wr = (const float*)d_in[10]; // br dropped: constant over j -> softmax-invariant

  const size_t need = ((size_t)4 * QKV_N + SCORES_N) * sizeof(float);
  if (ws_size < need) return;  // workspace too small: fail loudly via wrong output

  float* q      = (float*)d_ws;
  float* k      = q + QKV_N;
  float* v      = k + QKV_N;
  float* qr     = v + QKV_N;
  float* scores = qr + QKV_N;

  k_qkv<<<dim3(32, 36), 256, 0, stream>>>(x, Wq, bq, Wk, bk, Wv, bv, q);
  k_qr<<<dim3(8, NH, B), 256, 0, stream>>>(q, Wr, qr);
  k_qk<<<dim3(8, 8, B * NH), 256, 0, stream>>>(q, k, graph, endm, scores);
  k_rel<<<dim3(S / 2, B), 256, 0, stream>>>(qr, rel, scores);
  k_softmax<<<dim3(B * NH * S), 64, 0, stream>>>(scores);
  k_pv<<<dim3(16, NH, B), 256, 0, stream>>>(scores, v, (float*)d_out);
}

// Round 2
// 203.668 us; speedup vs baseline: 1.1650x; 1.1650x over previous
//
#include <hip/hip_runtime.h>
#include <hip/hip_bf16.h>
#include <cstddef>
#include <cstdint>

typedef __attribute__((ext_vector_type(8))) short bf16x8;
typedef __attribute__((ext_vector_type(4))) float f32x4;

#define MFMA16(a, b, c) __builtin_amdgcn_mfma_f32_16x16x32_bf16((a), (b), (c), 0, 0, 0)

static constexpr int B = 4, S = 512, HID = 768, NH = 12, HD = 64;
static constexpr int QKV_N = B * NH * S * HD;              // elems per q/k/v matrix
static constexpr size_t SCORES_N = (size_t)B * NH * S * S; // 12,582,912

// f32 -> bf16 round-to-nearest-even (inputs finite)
__device__ __forceinline__ short f2bf(float f) {
  unsigned u = __builtin_bit_cast(unsigned, f);
  u += 0x7FFFu + ((u >> 16) & 1u);
  return (short)(u >> 16);
}
__device__ __forceinline__ float bf2f(short s) {
  unsigned u = ((unsigned)(unsigned short)s) << 16;
  return __builtin_bit_cast(float, u);
}
// load 8 consecutive f32 and convert to a bf16x8 MFMA fragment
__device__ __forceinline__ bf16x8 ld_cvt8(const float* __restrict__ p) {
  float4 a = *reinterpret_cast<const float4*>(p);
  float4 b = *reinterpret_cast<const float4*>(p + 4);
  bf16x8 r;
  r[0] = f2bf(a.x); r[1] = f2bf(a.y); r[2] = f2bf(a.z); r[3] = f2bf(a.w);
  r[4] = f2bf(b.x); r[5] = f2bf(b.y); r[6] = f2bf(b.z); r[7] = f2bf(b.w);
  return r;
}

// ---------------------------------------------------------------------------
// K1: fused QKV projection -> bf16 outputs [mat][b][h][i/j][d]
// ---------------------------------------------------------------------------
__global__ __launch_bounds__(256) void k_qkv(
    const float* __restrict__ x,
    const float* __restrict__ Wq, const float* __restrict__ bq,
    const float* __restrict__ Wk, const float* __restrict__ bk,
    const float* __restrict__ Wv, const float* __restrict__ bv,
    short* __restrict__ qkv) {
  __shared__ short As[64 * 40];
  __shared__ short Bs[64 * 40];
  const int m0 = blockIdx.x * 64;
  const int nt = blockIdx.y;          // 0..35
  const int mat = nt / 12;
  const int nc0 = (nt % 12) * 64;
  const float* __restrict__ W    = (mat == 0) ? Wq : (mat == 1) ? Wk : Wv;
  const float* __restrict__ bias = (mat == 0) ? bq : (mat == 1) ? bk : bv;
  short* __restrict__ outp = qkv + (size_t)mat * QKV_N;
  const int t = threadIdx.x;
  const int w = t >> 6, lane = t & 63;
  const int wm = (w >> 1) * 32, wn = (w & 1) * 32;
  const int lr = lane & 15, lk = lane >> 4;
  f32x4 acc[2][2] = {};
  for (int kk = 0; kk < 768; kk += 32) {
#pragma unroll
    for (int it = 0; it < 2; ++it) {
      int f = it * 256 + t;
      {  // A tile: 64 rows x 32 k
        int r = f >> 3, c4 = f & 7;
        float4 v = *reinterpret_cast<const float4*>(x + (size_t)(m0 + r) * 768 + kk + c4 * 4);
        short* d = &As[r * 40 + c4 * 4];
        d[0] = f2bf(v.x); d[1] = f2bf(v.y); d[2] = f2bf(v.z); d[3] = f2bf(v.w);
      }
      {  // B tile transposed
        int kr = f >> 4, c4 = f & 15;
        float4 v = *reinterpret_cast<const float4*>(W + (size_t)(kk + kr) * 768 + nc0 + c4 * 4);
        int c = c4 * 4;
        Bs[(c + 0) * 40 + kr] = f2bf(v.x);
        Bs[(c + 1) * 40 + kr] = f2bf(v.y);
        Bs[(c + 2) * 40 + kr] = f2bf(v.z);
        Bs[(c + 3) * 40 + kr] = f2bf(v.w);
      }
    }
    __syncthreads();
    bf16x8 a0 = *reinterpret_cast<const bf16x8*>(&As[(wm + lr) * 40 + lk * 8]);
    bf16x8 a1 = *reinterpret_cast<const bf16x8*>(&As[(wm + 16 + lr) * 40 + lk * 8]);
    bf16x8 b0 = *reinterpret_cast<const bf16x8*>(&Bs[(wn + lr) * 40 + lk * 8]);
    bf16x8 b1 = *reinterpret_cast<const bf16x8*>(&Bs[(wn + 16 + lr) * 40 + lk * 8]);
    acc[0][0] = MFMA16(a0, b0, acc[0][0]);
    acc[0][1] = MFMA16(a0, b1, acc[0][1]);
    acc[1][0] = MFMA16(a1, b0, acc[1][0]);
    acc[1][1] = MFMA16(a1, b1, acc[1][1]);
    __syncthreads();
  }
#pragma unroll
  for (int mf = 0; mf < 2; ++mf)
#pragma unroll
    for (int nf = 0; nf < 2; ++nf) {
      int col = nc0 + wn + nf * 16 + lr;
      float bv_ = bias[col];
      int h = col >> 6, d = col & 63;
#pragma unroll
      for (int reg = 0; reg < 4; ++reg) {
        int m = m0 + wm + mf * 16 + lk * 4 + reg;
        int b_ = m >> 9, i = m & 511;
        outp[(size_t)((b_ * NH + h) * S + i) * HD + d] = f2bf(acc[mf][nf][reg] + bv_);
      }
    }
}

// ---------------------------------------------------------------------------
// K2: qr[b,h,i,r] = 0.125 * q[b,h,i,:] . Wr[r,:]  -> bf16
// ---------------------------------------------------------------------------
__global__ __launch_bounds__(256) void k_qr(const short* __restrict__ q,
                                            const float* __restrict__ Wr,
                                            short* __restrict__ qr) {
  const int i0 = blockIdx.x * 64;
  const int h = blockIdx.y, b = blockIdx.z;
  const short* __restrict__ qp = q + (size_t)((b * NH + h) * S) * HD;
  short* __restrict__ op = qr + (size_t)((b * NH + h) * S) * HD;
  const int t = threadIdx.x;
  const int w = t >> 6, lane = t & 63;
  const int wm = (w >> 1) * 32, wn = (w & 1) * 32;
  const int lr = lane & 15, lk = lane >> 4;
  f32x4 acc[2][2] = {};
#pragma unroll
  for (int ks = 0; ks < 2; ++ks) {
    int k0 = ks * 32 + lk * 8;
    bf16x8 a0 = *reinterpret_cast<const bf16x8*>(qp + (size_t)(i0 + wm + lr) * 64 + k0);
    bf16x8 a1 = *reinterpret_cast<const bf16x8*>(qp + (size_t)(i0 + wm + 16 + lr) * 64 + k0);
    bf16x8 b0 = ld_cvt8(Wr + (size_t)(wn + lr) * 64 + k0);
    bf16x8 b1 = ld_cvt8(Wr + (size_t)(wn + 16 + lr) * 64 + k0);
    acc[0][0] = MFMA16(a0, b0, acc[0][0]);
    acc[0][1] = MFMA16(a0, b1, acc[0][1]);
    acc[1][0] = MFMA16(a1, b0, acc[1][0]);
    acc[1][1] = MFMA16(a1, b1, acc[1][1]);
  }
#pragma unroll
  for (int mf = 0; mf < 2; ++mf)
#pragma unroll
    for (int nf = 0; nf < 2; ++nf) {
      int r = wn + nf * 16 + lr;
#pragma unroll
      for (int reg = 0; reg < 4; ++reg) {
        int i = i0 + wm + mf * 16 + lk * 4 + reg;
        op[(size_t)i * 64 + r] = f2bf(acc[mf][nf][reg] * 0.125f);
      }
    }
}

// ---------------------------------------------------------------------------
// K3: qk scores f32: 0.125*q.k + (1 - graph - end)*(-1e9)   [b,h,i,j]
// ---------------------------------------------------------------------------
__global__ __launch_bounds__(256) void k_qk(const short* __restrict__ q,
                                            const short* __restrict__ kmat,
                                            const float* __restrict__ graph,
                                            const float* __restrict__ endm,
                                            float* __restrict__ scores) {
  const int j0 = blockIdx.x * 64, i0 = blockIdx.y * 64;
  const int bh = blockIdx.z;
  const int b = bh / NH;
  const short* __restrict__ qp = q + (size_t)(bh * S) * HD;
  const short* __restrict__ kp = kmat + (size_t)(bh * S) * HD;
  const int t = threadIdx.x;
  const int w = t >> 6, lane = t & 63;
  const int wm = (w >> 1) * 32, wn = (w & 1) * 32;
  const int lr = lane & 15, lk = lane >> 4;
  f32x4 acc[2][2] = {};
#pragma unroll
  for (int ks = 0; ks < 2; ++ks) {
    int k0 = ks * 32 + lk * 8;
    bf16x8 a0 = *reinterpret_cast<const bf16x8*>(qp + (size_t)(i0 + wm + lr) * 64 + k0);
    bf16x8 a1 = *reinterpret_cast<const bf16x8*>(qp + (size_t)(i0 + wm + 16 + lr) * 64 + k0);
    bf16x8 b0 = *reinterpret_cast<const bf16x8*>(kp + (size_t)(j0 + wn + lr) * 64 + k0);
    bf16x8 b1 = *reinterpret_cast<const bf16x8*>(kp + (size_t)(j0 + wn + 16 + lr) * 64 + k0);
    acc[0][0] = MFMA16(a0, b0, acc[0][0]);
    acc[0][1] = MFMA16(a0, b1, acc[0][1]);
    acc[1][0] = MFMA16(a1, b0, acc[1][0]);
    acc[1][1] = MFMA16(a1, b1, acc[1][1]);
  }
#pragma unroll
  for (int mf = 0; mf < 2; ++mf)
#pragma unroll
    for (int nf = 0; nf < 2; ++nf) {
      int j = j0 + wn + nf * 16 + lr;
      float e = endm[b * S + j];
#pragma unroll
      for (int reg = 0; reg < 4; ++reg) {
        int i = i0 + wm + mf * 16 + lk * 4 + reg;
        float g = graph[(size_t)(b * S + i) * S + j];
        scores[((size_t)bh * S + i) * S + j] =
            acc[mf][nf][reg] * 0.125f + (1.0f - g - e) * (-1e9f);
      }
    }
}

// ---------------------------------------------------------------------------
// K4 (fused): per (b,i): s = qk_scores + qr . rel^T ; p = exp(min(s,80));
// den-reduce; write normalized probs bf16 [b,h,i,j].
// Clamp trick: reference max-softmax == ours exactly (only the g+e=2 column
// can exceed 80 -> saturates its row identically; masked -1e9 -> exp = 0).
// ---------------------------------------------------------------------------
__global__ __launch_bounds__(256) void k_relsm(const short* __restrict__ qrb,
                                               const float* __restrict__ rel,
                                               const float* __restrict__ scores,
                                               short* __restrict__ probs) {
  __shared__ float sq[16 * 516];   // [h][j], stride 516 -> 2-way (free) banks
  __shared__ float den_lds[64];
  const int i = blockIdx.x, b = blockIdx.y;
  const int t = threadIdx.x;
  const int w = t >> 6, lane = t & 63;
  const int lr = lane & 15, fq = lane >> 4;
  // stage qk-score rows, zero the 4 pad rows
#pragma unroll
  for (int it = 0; it < 8; ++it) {
    int f = it * 256 + t;
    int h = f >> 7, j4 = f & 127;
    float4 v = make_float4(0.f, 0.f, 0.f, 0.f);
    if (h < NH)
      v = *reinterpret_cast<const float4*>(scores + ((size_t)(b * NH + h) * S + i) * S + j4 * 4);
    *reinterpret_cast<float4*>(&sq[h * 516 + j4 * 4]) = v;
  }
  const int hA = (lr < NH) ? lr : 0;  // clamp A pad rows (outputs discarded)
  const short* qrow = qrb + ((size_t)(b * NH + hA) * S + i) * 64;
  bf16x8 a0 = *reinterpret_cast<const bf16x8*>(qrow + fq * 8);
  bf16x8 a1 = *reinterpret_cast<const bf16x8*>(qrow + 32 + fq * 8);
  __syncthreads();
  const float* rp = rel + ((size_t)(b * S) + i) * S * 64;
  float p[8][4];
  float den[4] = {0.f, 0.f, 0.f, 0.f};
#pragma unroll
  for (int tt = 0; tt < 8; ++tt) {
    int j0 = w * 128 + tt * 16;
    const float* rrow = rp + (size_t)(j0 + lr) * 64 + fq * 8;
    bf16x8 b0 = ld_cvt8(rrow);
    bf16x8 b1 = ld_cvt8(rrow + 32);
    f32x4 acc = {};
    acc = MFMA16(a0, b0, acc);
    acc = MFMA16(a1, b1, acc);
#pragma unroll
    for (int r = 0; r < 4; ++r) {
      int h = fq * 4 + r;
      float s = acc[r] + sq[h * 516 + j0 + lr];
      float pe = __expf(fminf(s, 80.0f));
      p[tt][r] = pe;
      den[r] += pe;
    }
  }
#pragma unroll
  for (int r = 0; r < 4; ++r) {
    float d = den[r];
    d += __shfl_xor(d, 1); d += __shfl_xor(d, 2);
    d += __shfl_xor(d, 4); d += __shfl_xor(d, 8);
    den[r] = d;
  }
  if (lr == 0) {
#pragma unroll
    for (int r = 0; r < 4; ++r) den_lds[w * 16 + fq * 4 + r] = den[r];
  }
  __syncthreads();
  float invd[4];
#pragma unroll
  for (int r = 0; r < 4; ++r) {
    int h = fq * 4 + r;
    invd[r] = 1.0f / (den_lds[h] + den_lds[16 + h] + den_lds[32 + h] + den_lds[48 + h]);
  }
#pragma unroll
  for (int tt = 0; tt < 8; ++tt) {
    int j0 = w * 128 + tt * 16;
#pragma unroll
    for (int r = 0; r < 4; ++r) {
      int h = fq * 4 + r;
      if (h < NH)
        probs[((size_t)(b * NH + h) * S + i) * S + j0 + lr] = f2bf(p[tt][r] * invd[r]);
    }
  }
}

// ---------------------------------------------------------------------------
// K5: ctx = probs @ v  (bf16 in, f32 out), VALU with LDS tiles.
// ---------------------------------------------------------------------------
__global__ __launch_bounds__(256) void k_pv(const short* __restrict__ probs,
                                            const short* __restrict__ v,
                                            float* __restrict__ out) {
  __shared__ float vs[64 * 64];   // [j][d]
  __shared__ float ps[32 * 68];   // [i][j]
  const int i0 = blockIdx.x * 32;
  const int h = blockIdx.y, b = blockIdx.z;
  const int t = threadIdx.x;
  const int il = t >> 3, dg = t & 7;
  const short* __restrict__ vp = v + (size_t)((b * NH + h) * S) * HD;
  const short* __restrict__ pp = probs + ((size_t)(b * NH + h) * S + i0) * S;
  float acc[8] = {};
  for (int jt = 0; jt < 8; ++jt) {
    int j0 = jt * 64;
    __syncthreads();
#pragma unroll
    for (int it = 0; it < 2; ++it) {
      int f = it * 256 + t;
      int jr = f >> 3, c8 = f & 7;
      bf16x8 vv = *reinterpret_cast<const bf16x8*>(vp + (size_t)(j0 + jr) * 64 + c8 * 8);
      float* d = &vs[jr * 64 + c8 * 8];
#pragma unroll
      for (int u = 0; u < 8; ++u) d[u] = bf2f(vv[u]);
    }
    {
      int ir = t >> 3, c8 = t & 7;
      bf16x8 pv8 = *reinterpret_cast<const bf16x8*>(pp + (size_t)ir * S + j0 + c8 * 8);
      float* d = &ps[ir * 68 + c8 * 8];
#pragma unroll
      for (int u = 0; u < 8; ++u) d[u] = bf2f(pv8[u]);
    }
    __syncthreads();
#pragma unroll 8
    for (int j = 0; j < 64; ++j) {
      float pval = ps[il * 68 + j];
      const float* vrow = &vs[j * 64 + dg * 8];
#pragma unroll
      for (int u = 0; u < 8; ++u) acc[u] = fmaf(pval, vrow[u], acc[u]);
    }
  }
  float* __restrict__ op = out + ((size_t)(b * S) + i0 + il) * HID + h * 64 + dg * 8;
#pragma unroll
  for (int u = 0; u < 8; ++u) op[u] = acc[u];
}

// ---------------------------------------------------------------------------
extern "C" void kernel_launch(void* const* d_in, const int* in_sizes, int n_in,
                              void* d_out, int out_size, void* d_ws, size_t ws_size,
                              hipStream_t stream) {
  const float* x     = (const float*)d_in[0];
  const float* graph = (const float*)d_in[1];
  const float* endm  = (const float*)d_in[2];
  const float* rel   = (const float*)d_in[3];
  const float* Wq = (const float*)d_in[4];  const float* bq = (const float*)d_in[5];
  const float* Wk = (const float*)d_in[6];  const float* bk = (const float*)d_in[7];
  const float* Wv = (const float*)d_in[8];  const float* bv = (const float*)d_in[9];
  const float* Wr = (const float*)d_in[10]; // br dropped: softmax-invariant

  short* qb  = (short*)d_ws;
  short* kb  = qb + QKV_N;
  short* vb  = kb + QKV_N;
  short* qrb = vb + QKV_N;
  float* scores = (float*)(qrb + QKV_N);
  short* probs  = (short*)(scores + SCORES_N);
  const size_t need = (size_t)4 * QKV_N * 2 + SCORES_N * 4 + SCORES_N * 2;
  if (ws_size < need) return;

  k_qkv<<<dim3(32, 36), 256, 0, stream>>>(x, Wq, bq, Wk, bk, Wv, bv, qb);
  k_qr<<<dim3(8, NH, B), 256, 0, stream>>>(qb, Wr, qrb);
  k_qk<<<dim3(8, 8, B * NH), 256, 0, stream>>>(qb, kb, graph, endm, scores);
  k_relsm<<<dim3(S, B), 256, 0, stream>>>(qrb, rel, scores, probs);
  k_pv<<<dim3(16, NH, B), 256, 0, stream>>>(probs, vb, (float*)d_out);
}

// Round 3
// 173.317 us; speedup vs baseline: 1.3690x; 1.1751x over previous
//
#include <hip/hip_runtime.h>
#include <hip/hip_bf16.h>
#include <cstddef>
#include <cstdint>

typedef __attribute__((ext_vector_type(8))) short bf16x8;
typedef __attribute__((ext_vector_type(4))) float f32x4;

#define MFMA16(a, b, c) __builtin_amdgcn_mfma_f32_16x16x32_bf16((a), (b), (c), 0, 0, 0)

static constexpr int B = 4, S = 512, HID = 768, NH = 12, HD = 64;
static constexpr int QKV_N = B * NH * S * HD;
static constexpr size_t SCORES_N = (size_t)B * NH * S * S;

__device__ __forceinline__ short f2bf(float f) {
  unsigned u = __builtin_bit_cast(unsigned, f);
  u += 0x7FFFu + ((u >> 16) & 1u);
  return (short)(u >> 16);
}
__device__ __forceinline__ float bf2f(short s) {
  unsigned u = ((unsigned)(unsigned short)s) << 16;
  return __builtin_bit_cast(float, u);
}
__device__ __forceinline__ bf16x8 ld_cvt8(const float* __restrict__ p) {
  float4 a = *reinterpret_cast<const float4*>(p);
  float4 b = *reinterpret_cast<const float4*>(p + 4);
  bf16x8 r;
  r[0] = f2bf(a.x); r[1] = f2bf(a.y); r[2] = f2bf(a.z); r[3] = f2bf(a.w);
  r[4] = f2bf(b.x); r[5] = f2bf(b.y); r[6] = f2bf(b.z); r[7] = f2bf(b.w);
  return r;
}

// ---------------------------------------------------------------------------
// K1: fused QKV projection -> bf16 [mat][b][h][row][d]
// ---------------------------------------------------------------------------
__global__ __launch_bounds__(256) void k_qkv(
    const float* __restrict__ x,
    const float* __restrict__ Wq, const float* __restrict__ bq,
    const float* __restrict__ Wk, const float* __restrict__ bk,
    const float* __restrict__ Wv, const float* __restrict__ bv,
    short* __restrict__ qkv) {
  __shared__ short As[64 * 40];
  __shared__ short Bs[64 * 40];
  const int m0 = blockIdx.x * 64;
  const int nt = blockIdx.y;
  const int mat = nt / 12;
  const int nc0 = (nt % 12) * 64;
  const float* __restrict__ W    = (mat == 0) ? Wq : (mat == 1) ? Wk : Wv;
  const float* __restrict__ bias = (mat == 0) ? bq : (mat == 1) ? bk : bv;
  short* __restrict__ outp = qkv + (size_t)mat * QKV_N;
  const int t = threadIdx.x;
  const int w = t >> 6, lane = t & 63;
  const int wm = (w >> 1) * 32, wn = (w & 1) * 32;
  const int lr = lane & 15, lk = lane >> 4;
  f32x4 acc[2][2] = {};
  for (int kk = 0; kk < 768; kk += 32) {
#pragma unroll
    for (int it = 0; it < 2; ++it) {
      int f = it * 256 + t;
      {
        int r = f >> 3, c4 = f & 7;
        float4 v = *reinterpret_cast<const float4*>(x + (size_t)(m0 + r) * 768 + kk + c4 * 4);
        short* d = &As[r * 40 + c4 * 4];
        d[0] = f2bf(v.x); d[1] = f2bf(v.y); d[2] = f2bf(v.z); d[3] = f2bf(v.w);
      }
      {
        int kr = f >> 4, c4 = f & 15;
        float4 v = *reinterpret_cast<const float4*>(W + (size_t)(kk + kr) * 768 + nc0 + c4 * 4);
        int c = c4 * 4;
        Bs[(c + 0) * 40 + kr] = f2bf(v.x);
        Bs[(c + 1) * 40 + kr] = f2bf(v.y);
        Bs[(c + 2) * 40 + kr] = f2bf(v.z);
        Bs[(c + 3) * 40 + kr] = f2bf(v.w);
      }
    }
    __syncthreads();
    bf16x8 a0 = *reinterpret_cast<const bf16x8*>(&As[(wm + lr) * 40 + lk * 8]);
    bf16x8 a1 = *reinterpret_cast<const bf16x8*>(&As[(wm + 16 + lr) * 40 + lk * 8]);
    bf16x8 b0 = *reinterpret_cast<const bf16x8*>(&Bs[(wn + lr) * 40 + lk * 8]);
    bf16x8 b1 = *reinterpret_cast<const bf16x8*>(&Bs[(wn + 16 + lr) * 40 + lk * 8]);
    acc[0][0] = MFMA16(a0, b0, acc[0][0]);
    acc[0][1] = MFMA16(a0, b1, acc[0][1]);
    acc[1][0] = MFMA16(a1, b0, acc[1][0]);
    acc[1][1] = MFMA16(a1, b1, acc[1][1]);
    __syncthreads();
  }
#pragma unroll
  for (int mf = 0; mf < 2; ++mf)
#pragma unroll
    for (int nf = 0; nf < 2; ++nf) {
      int col = nc0 + wn + nf * 16 + lr;
      float bv_ = bias[col];
      int h = col >> 6, d = col & 63;
#pragma unroll
      for (int reg = 0; reg < 4; ++reg) {
        int m = m0 + wm + mf * 16 + lk * 4 + reg;
        int b_ = m >> 9, i = m & 511;
        outp[(size_t)((b_ * NH + h) * S + i) * HD + d] = f2bf(acc[mf][nf][reg] + bv_);
      }
    }
}

// ---------------------------------------------------------------------------
// K2: qr = 0.125 * q @ Wr^T  -> bf16
// ---------------------------------------------------------------------------
__global__ __launch_bounds__(256) void k_qr(const short* __restrict__ q,
                                            const float* __restrict__ Wr,
                                            short* __restrict__ qr) {
  const int i0 = blockIdx.x * 64;
  const int h = blockIdx.y, b = blockIdx.z;
  const short* __restrict__ qp = q + (size_t)((b * NH + h) * S) * HD;
  short* __restrict__ op = qr + (size_t)((b * NH + h) * S) * HD;
  const int t = threadIdx.x;
  const int w = t >> 6, lane = t & 63;
  const int wm = (w >> 1) * 32, wn = (w & 1) * 32;
  const int lr = lane & 15, lk = lane >> 4;
  f32x4 acc[2][2] = {};
#pragma unroll
  for (int ks = 0; ks < 2; ++ks) {
    int k0 = ks * 32 + lk * 8;
    bf16x8 a0 = *reinterpret_cast<const bf16x8*>(qp + (size_t)(i0 + wm + lr) * 64 + k0);
    bf16x8 a1 = *reinterpret_cast<const bf16x8*>(qp + (size_t)(i0 + wm + 16 + lr) * 64 + k0);
    bf16x8 b0 = ld_cvt8(Wr + (size_t)(wn + lr) * 64 + k0);
    bf16x8 b1 = ld_cvt8(Wr + (size_t)(wn + 16 + lr) * 64 + k0);
    acc[0][0] = MFMA16(a0, b0, acc[0][0]);
    acc[0][1] = MFMA16(a0, b1, acc[0][1]);
    acc[1][0] = MFMA16(a1, b0, acc[1][0]);
    acc[1][1] = MFMA16(a1, b1, acc[1][1]);
  }
#pragma unroll
  for (int mf = 0; mf < 2; ++mf)
#pragma unroll
    for (int nf = 0; nf < 2; ++nf) {
      int r = wn + nf * 16 + lr;
#pragma unroll
      for (int reg = 0; reg < 4; ++reg) {
        int i = i0 + wm + mf * 16 + lk * 4 + reg;
        op[(size_t)i * 64 + r] = f2bf(acc[mf][nf][reg] * 0.125f);
      }
    }
}

// ---------------------------------------------------------------------------
// K3: qk scores f32: 0.125*q.k + (1 - graph - end)*(-1e9)
// ---------------------------------------------------------------------------
__global__ __launch_bounds__(256) void k_qk(const short* __restrict__ q,
                                            const short* __restrict__ kmat,
                                            const float* __restrict__ graph,
                                            const float* __restrict__ endm,
                                            float* __restrict__ scores) {
  const int j0 = blockIdx.x * 64, i0 = blockIdx.y * 64;
  const int bh = blockIdx.z;
  const int b = bh / NH;
  const short* __restrict__ qp = q + (size_t)(bh * S) * HD;
  const short* __restrict__ kp = kmat + (size_t)(bh * S) * HD;
  const int t = threadIdx.x;
  const int w = t >> 6, lane = t & 63;
  const int wm = (w >> 1) * 32, wn = (w & 1) * 32;
  const int lr = lane & 15, lk = lane >> 4;
  f32x4 acc[2][2] = {};
#pragma unroll
  for (int ks = 0; ks < 2; ++ks) {
    int k0 = ks * 32 + lk * 8;
    bf16x8 a0 = *reinterpret_cast<const bf16x8*>(qp + (size_t)(i0 + wm + lr) * 64 + k0);
    bf16x8 a1 = *reinterpret_cast<const bf16x8*>(qp + (size_t)(i0 + wm + 16 + lr) * 64 + k0);
    bf16x8 b0 = *reinterpret_cast<const bf16x8*>(kp + (size_t)(j0 + wn + lr) * 64 + k0);
    bf16x8 b1 = *reinterpret_cast<const bf16x8*>(kp + (size_t)(j0 + wn + 16 + lr) * 64 + k0);
    acc[0][0] = MFMA16(a0, b0, acc[0][0]);
    acc[0][1] = MFMA16(a0, b1, acc[0][1]);
    acc[1][0] = MFMA16(a1, b0, acc[1][0]);
    acc[1][1] = MFMA16(a1, b1, acc[1][1]);
  }
#pragma unroll
  for (int mf = 0; mf < 2; ++mf)
#pragma unroll
    for (int nf = 0; nf < 2; ++nf) {
      int j = j0 + wn + nf * 16 + lr;
      float e = endm[b * S + j];
#pragma unroll
      for (int reg = 0; reg < 4; ++reg) {
        int i = i0 + wm + mf * 16 + lk * 4 + reg;
        float g = graph[(size_t)(b * S + i) * S + j];
        scores[((size_t)bh * S + i) * S + j] =
            acc[mf][nf][reg] * 0.125f + (1.0f - g - e) * (-1e9f);
      }
    }
}

// ---------------------------------------------------------------------------
// K4: per (b,i): s = scores + qr.rel^T; p = exp(min(s,80)); den-reduce;
// probs = p/den (bf16). No sq stage (direct strided score reads); p buffered
// in LDS bf16 -> low VGPR, vectorized coalesced output pass.
// ---------------------------------------------------------------------------
__global__ __launch_bounds__(256) void k_relsm(const short* __restrict__ qrb,
                                               const float* __restrict__ rel,
                                               const float* __restrict__ scores,
                                               short* __restrict__ probs) {
  __shared__ short pl[16 * 520];   // [h][j] unnormalized p, bf16
  __shared__ float den_lds[64];
  const int i = blockIdx.x, b = blockIdx.y;
  const int t = threadIdx.x;
  const int w = t >> 6, lane = t & 63;
  const int lr = lane & 15, fq = lane >> 4;
  const int hA = (lr < NH) ? lr : 0;  // clamp pad A-rows (outputs discarded)
  const short* qrow = qrb + ((size_t)(b * NH + hA) * S + i) * 64;
  bf16x8 a0 = *reinterpret_cast<const bf16x8*>(qrow + fq * 8);
  bf16x8 a1 = *reinterpret_cast<const bf16x8*>(qrow + 32 + fq * 8);
  const float* rp = rel + ((size_t)(b * S) + i) * S * 64;
  const float* sc = scores + ((size_t)(b * NH) * S + i) * S;  // + h*S*S + j
  float den[4] = {0.f, 0.f, 0.f, 0.f};
#pragma unroll
  for (int tt = 0; tt < 8; ++tt) {
    int j0 = w * 128 + tt * 16;
    const float* rrow = rp + (size_t)(j0 + lr) * 64 + fq * 8;
    bf16x8 b0 = ld_cvt8(rrow);
    bf16x8 b1 = ld_cvt8(rrow + 32);
    f32x4 acc = {};
    acc = MFMA16(a0, b0, acc);
    acc = MFMA16(a1, b1, acc);
#pragma unroll
    for (int r = 0; r < 4; ++r) {
      int h = fq * 4 + r;
      float s = acc[r] + sc[(size_t)h * S * S + j0 + lr];
      float pe = __expf(fminf(s, 80.0f));
      den[r] += pe;
      pl[h * 520 + j0 + lr] = f2bf(pe);
    }
  }
#pragma unroll
  for (int r = 0; r < 4; ++r) {
    float d = den[r];
    d += __shfl_xor(d, 1); d += __shfl_xor(d, 2);
    d += __shfl_xor(d, 4); d += __shfl_xor(d, 8);
    den[r] = d;
  }
  if (lr == 0) {
#pragma unroll
    for (int r = 0; r < 4; ++r) den_lds[w * 16 + fq * 4 + r] = den[r];
  }
  __syncthreads();
  // output pass: thread -> (h = t>>4, 32 j's at jseg*32)
  const int h = t >> 4, jseg = t & 15;
  if (h < NH) {
    float inv = 1.0f / (den_lds[h] + den_lds[16 + h] + den_lds[32 + h] + den_lds[48 + h]);
    short* op = probs + ((size_t)(b * NH + h) * S + i) * S + jseg * 32;
    const short* lp = &pl[h * 520 + jseg * 32];
#pragma unroll
    for (int c = 0; c < 4; ++c) {
      bf16x8 x = *reinterpret_cast<const bf16x8*>(lp + c * 8);
      bf16x8 y;
#pragma unroll
      for (int u = 0; u < 8; ++u) y[u] = f2bf(bf2f(x[u]) * inv);
      *reinterpret_cast<bf16x8*>(op + c * 8) = y;
    }
  }
}

// ---------------------------------------------------------------------------
// K5: ctx = probs @ v via MFMA. Block = 64i x 64d per (b,h); v tile
// LDS-transposed with XOR j-block swizzle (conflict-free b128 reads).
// ---------------------------------------------------------------------------
__global__ __launch_bounds__(256) void k_pv2(const short* __restrict__ probs,
                                             const short* __restrict__ v,
                                             float* __restrict__ out) {
  __shared__ short vt[64 * 72];  // [d][j-local], stride 72 shorts (144B)
  const int i0 = blockIdx.x * 64;
  const int h = blockIdx.y, b = blockIdx.z;
  const short* __restrict__ vp = v + (size_t)((b * NH + h) * S) * HD;
  const short* __restrict__ pp = probs + (size_t)((b * NH + h) * S) * S;
  const int t = threadIdx.x;
  const int w = t >> 6, lane = t & 63;
  const int wm = (w >> 1) * 32, wn = (w & 1) * 32;
  const int lr = lane & 15, lk = lane >> 4;
  f32x4 acc[2][2] = {};
  for (int j0 = 0; j0 < S; j0 += 64) {
    __syncthreads();
#pragma unroll
    for (int it = 0; it < 2; ++it) {
      int jr = it * 32 + (t >> 3), c8 = t & 7;
      bf16x8 vv = *reinterpret_cast<const bf16x8*>(vp + (size_t)(j0 + jr) * 64 + c8 * 8);
      int jsw = (((jr >> 3) ^ c8) << 3) | (jr & 7);
#pragma unroll
      for (int u = 0; u < 8; ++u) vt[(c8 * 8 + u) * 72 + jsw] = vv[u];
    }
    __syncthreads();
#pragma unroll
    for (int ks = 0; ks < 2; ++ks) {
      const short* prow = pp + j0 + ks * 32 + lk * 8;
      bf16x8 a0 = *reinterpret_cast<const bf16x8*>(prow + (size_t)(i0 + wm + lr) * S);
      bf16x8 a1 = *reinterpret_cast<const bf16x8*>(prow + (size_t)(i0 + wm + 16 + lr) * S);
      int r0 = wn + lr, r1 = wn + 16 + lr;
      int jb = ks * 4 + lk;
      bf16x8 b0 = *reinterpret_cast<const bf16x8*>(&vt[r0 * 72 + ((jb ^ ((r0 >> 3) & 7)) << 3)]);
      bf16x8 b1 = *reinterpret_cast<const bf16x8*>(&vt[r1 * 72 + ((jb ^ ((r1 >> 3) & 7)) << 3)]);
      acc[0][0] = MFMA16(a0, b0, acc[0][0]);
      acc[0][1] = MFMA16(a0, b1, acc[0][1]);
      acc[1][0] = MFMA16(a1, b0, acc[1][0]);
      acc[1][1] = MFMA16(a1, b1, acc[1][1]);
    }
  }
#pragma unroll
  for (int mf = 0; mf < 2; ++mf)
#pragma unroll
    for (int nf = 0; nf < 2; ++nf) {
      int d = wn + nf * 16 + lr;
#pragma unroll
      for (int reg = 0; reg < 4; ++reg) {
        int i = i0 + wm + mf * 16 + lk * 4 + reg;
        out[((size_t)(b * S) + i) * HID + h * 64 + d] = acc[mf][nf][reg];
      }
    }
}

// ---------------------------------------------------------------------------
extern "C" void kernel_launch(void* const* d_in, const int* in_sizes, int n_in,
                              void* d_out, int out_size, void* d_ws, size_t ws_size,
                              hipStream_t stream) {
  const float* x     = (const float*)d_in[0];
  const float* graph = (const float*)d_in[1];
  const float* endm  = (const float*)d_in[2];
  const float* rel   = (const float*)d_in[3];
  const float* Wq = (const float*)d_in[4];  const float* bq = (const float*)d_in[5];
  const float* Wk = (const float*)d_in[6];  const float* bk = (const float*)d_in[7];
  const float* Wv = (const float*)d_in[8];  const float* bv = (const float*)d_in[9];
  const float* Wr = (const float*)d_in[10]; // br dropped: softmax-invariant

  short* qb  = (short*)d_ws;
  short* kb  = qb + QKV_N;
  short* vb  = kb + QKV_N;
  short* qrb = vb + QKV_N;
  float* scores = (float*)(qrb + QKV_N);
  short* probs  = (short*)(scores + SCORES_N);
  const size_t need = (size_t)4 * QKV_N * 2 + SCORES_N * 4 + SCORES_N * 2;
  if (ws_size < need) return;

  k_qkv<<<dim3(32, 36), 256, 0, stream>>>(x, Wq, bq, Wk, bk, Wv, bv, qb);
  k_qr<<<dim3(8, NH, B), 256, 0, stream>>>(qb, Wr, qrb);
  k_qk<<<dim3(8, 8, B * NH), 256, 0, stream>>>(qb, kb, graph, endm, scores);
  k_relsm<<<dim3(S, B), 256, 0, stream>>>(qrb, rel, scores, probs);
  k_pv2<<<dim3(8, NH, B), 256, 0, stream>>>(probs, vb, (float*)d_out);
}

// Round 5
// 162.421 us; speedup vs baseline: 1.4609x; 1.0671x over previous
//
#include <hip/hip_runtime.h>
#include <hip/hip_bf16.h>
#include <hip/hip_fp16.h>
#include <cstddef>
#include <cstdint>

typedef __attribute__((ext_vector_type(8))) short bf16x8;
typedef __attribute__((ext_vector_type(4))) float f32x4;

#define MFMA16(a, b, c) __builtin_amdgcn_mfma_f32_16x16x32_bf16((a), (b), (c), 0, 0, 0)

static constexpr int B = 4, S = 512, HID = 768, NH = 12, HD = 64;
static constexpr int QKV_N = B * NH * S * HD;
static constexpr size_t SCORES_N = (size_t)B * NH * S * S;

__device__ __forceinline__ short f2bf(float f) {
  unsigned u = __builtin_bit_cast(unsigned, f);
  u += 0x7FFFu + ((u >> 16) & 1u);
  return (short)(u >> 16);
}
__device__ __forceinline__ float bf2f(short s) {
  unsigned u = ((unsigned)(unsigned short)s) << 16;
  return __builtin_bit_cast(float, u);
}
__device__ __forceinline__ bf16x8 ld_cvt8(const float* __restrict__ p) {
  float4 a = *reinterpret_cast<const float4*>(p);
  float4 b = *reinterpret_cast<const float4*>(p + 4);
  bf16x8 r;
  r[0] = f2bf(a.x); r[1] = f2bf(a.y); r[2] = f2bf(a.z); r[3] = f2bf(a.w);
  r[4] = f2bf(b.x); r[5] = f2bf(b.y); r[6] = f2bf(b.z); r[7] = f2bf(b.w);
  return r;
}
// nontemporal 16B load as native ext-vector (HIP float4 is rejected by builtin)
__device__ __forceinline__ f32x4 ld4nt(const float* p) {
  return __builtin_nontemporal_load(reinterpret_cast<const f32x4*>(p));
}
__device__ __forceinline__ bf16x8 cvt8(f32x4 a, f32x4 b) {
  bf16x8 r;
  r[0] = f2bf(a[0]); r[1] = f2bf(a[1]); r[2] = f2bf(a[2]); r[3] = f2bf(a[3]);
  r[4] = f2bf(b[0]); r[5] = f2bf(b[1]); r[6] = f2bf(b[2]); r[7] = f2bf(b[3]);
  return r;
}

// ---------------------------------------------------------------------------
// K1: fused QKV projection -> bf16 [mat][b][h][row][d]
// ---------------------------------------------------------------------------
__global__ __launch_bounds__(256) void k_qkv(
    const float* __restrict__ x,
    const float* __restrict__ Wq, const float* __restrict__ bq,
    const float* __restrict__ Wk, const float* __restrict__ bk,
    const float* __restrict__ Wv, const float* __restrict__ bv,
    short* __restrict__ qkv) {
  __shared__ short As[64 * 40];
  __shared__ short Bs[64 * 40];
  const int m0 = blockIdx.x * 64;
  const int nt = blockIdx.y;
  const int mat = nt / 12;
  const int nc0 = (nt % 12) * 64;
  const float* __restrict__ W    = (mat == 0) ? Wq : (mat == 1) ? Wk : Wv;
  const float* __restrict__ bias = (mat == 0) ? bq : (mat == 1) ? bk : bv;
  short* __restrict__ outp = qkv + (size_t)mat * QKV_N;
  const int t = threadIdx.x;
  const int w = t >> 6, lane = t & 63;
  const int wm = (w >> 1) * 32, wn = (w & 1) * 32;
  const int lr = lane & 15, lk = lane >> 4;
  f32x4 acc[2][2] = {};
  for (int kk = 0; kk < 768; kk += 32) {
#pragma unroll
    for (int it = 0; it < 2; ++it) {
      int f = it * 256 + t;
      {
        int r = f >> 3, c4 = f & 7;
        float4 v = *reinterpret_cast<const float4*>(x + (size_t)(m0 + r) * 768 + kk + c4 * 4);
        short* d = &As[r * 40 + c4 * 4];
        d[0] = f2bf(v.x); d[1] = f2bf(v.y); d[2] = f2bf(v.z); d[3] = f2bf(v.w);
      }
      {
        int kr = f >> 4, c4 = f & 15;
        float4 v = *reinterpret_cast<const float4*>(W + (size_t)(kk + kr) * 768 + nc0 + c4 * 4);
        int c = c4 * 4;
        Bs[(c + 0) * 40 + kr] = f2bf(v.x);
        Bs[(c + 1) * 40 + kr] = f2bf(v.y);
        Bs[(c + 2) * 40 + kr] = f2bf(v.z);
        Bs[(c + 3) * 40 + kr] = f2bf(v.w);
      }
    }
    __syncthreads();
    bf16x8 a0 = *reinterpret_cast<const bf16x8*>(&As[(wm + lr) * 40 + lk * 8]);
    bf16x8 a1 = *reinterpret_cast<const bf16x8*>(&As[(wm + 16 + lr) * 40 + lk * 8]);
    bf16x8 b0 = *reinterpret_cast<const bf16x8*>(&Bs[(wn + lr) * 40 + lk * 8]);
    bf16x8 b1 = *reinterpret_cast<const bf16x8*>(&Bs[(wn + 16 + lr) * 40 + lk * 8]);
    acc[0][0] = MFMA16(a0, b0, acc[0][0]);
    acc[0][1] = MFMA16(a0, b1, acc[0][1]);
    acc[1][0] = MFMA16(a1, b0, acc[1][0]);
    acc[1][1] = MFMA16(a1, b1, acc[1][1]);
    __syncthreads();
  }
#pragma unroll
  for (int mf = 0; mf < 2; ++mf)
#pragma unroll
    for (int nf = 0; nf < 2; ++nf) {
      int col = nc0 + wn + nf * 16 + lr;
      float bv_ = bias[col];
      int h = col >> 6, d = col & 63;
#pragma unroll
      for (int reg = 0; reg < 4; ++reg) {
        int m = m0 + wm + mf * 16 + lk * 4 + reg;
        int b_ = m >> 9, i = m & 511;
        outp[(size_t)((b_ * NH + h) * S + i) * HD + d] = f2bf(acc[mf][nf][reg] + bv_);
      }
    }
}

// ---------------------------------------------------------------------------
// K2: qr = 0.125 * q @ Wr^T  -> bf16
// ---------------------------------------------------------------------------
__global__ __launch_bounds__(256) void k_qr(const short* __restrict__ q,
                                            const float* __restrict__ Wr,
                                            short* __restrict__ qr) {
  const int i0 = blockIdx.x * 64;
  const int h = blockIdx.y, b = blockIdx.z;
  const short* __restrict__ qp = q + (size_t)((b * NH + h) * S) * HD;
  short* __restrict__ op = qr + (size_t)((b * NH + h) * S) * HD;
  const int t = threadIdx.x;
  const int w = t >> 6, lane = t & 63;
  const int wm = (w >> 1) * 32, wn = (w & 1) * 32;
  const int lr = lane & 15, lk = lane >> 4;
  f32x4 acc[2][2] = {};
#pragma unroll
  for (int ks = 0; ks < 2; ++ks) {
    int k0 = ks * 32 + lk * 8;
    bf16x8 a0 = *reinterpret_cast<const bf16x8*>(qp + (size_t)(i0 + wm + lr) * 64 + k0);
    bf16x8 a1 = *reinterpret_cast<const bf16x8*>(qp + (size_t)(i0 + wm + 16 + lr) * 64 + k0);
    bf16x8 b0 = ld_cvt8(Wr + (size_t)(wn + lr) * 64 + k0);
    bf16x8 b1 = ld_cvt8(Wr + (size_t)(wn + 16 + lr) * 64 + k0);
    acc[0][0] = MFMA16(a0, b0, acc[0][0]);
    acc[0][1] = MFMA16(a0, b1, acc[0][1]);
    acc[1][0] = MFMA16(a1, b0, acc[1][0]);
    acc[1][1] = MFMA16(a1, b1, acc[1][1]);
  }
#pragma unroll
  for (int mf = 0; mf < 2; ++mf)
#pragma unroll
    for (int nf = 0; nf < 2; ++nf) {
      int r = wn + nf * 16 + lr;
#pragma unroll
      for (int reg = 0; reg < 4; ++reg) {
        int i = i0 + wm + mf * 16 + lk * 4 + reg;
        op[(size_t)i * 64 + r] = f2bf(acc[mf][nf][reg] * 0.125f);
      }
    }
}

// ---------------------------------------------------------------------------
// K3: qk scores -> f16, layout [b][i][h][j].
// s = 0.125*q.k + (1-g-e)*(-30000): masked -> exp==0 exactly; g+e==2 -> +30000
// saturates via the min(s,80) clamp in relsm, identical to reference +1e9.
// ---------------------------------------------------------------------------
__global__ __launch_bounds__(256) void k_qk(const short* __restrict__ q,
                                            const short* __restrict__ kmat,
                                            const float* __restrict__ graph,
                                            const float* __restrict__ endm,
                                            __half* __restrict__ sc) {
  const int j0 = blockIdx.x * 64, i0 = blockIdx.y * 64;
  const int bh = blockIdx.z;
  const int b = bh / NH, hh = bh % NH;
  const short* __restrict__ qp = q + (size_t)(bh * S) * HD;
  const short* __restrict__ kp = kmat + (size_t)(bh * S) * HD;
  const int t = threadIdx.x;
  const int w = t >> 6, lane = t & 63;
  const int wm = (w >> 1) * 32, wn = (w & 1) * 32;
  const int lr = lane & 15, lk = lane >> 4;
  f32x4 acc[2][2] = {};
#pragma unroll
  for (int ks = 0; ks < 2; ++ks) {
    int k0 = ks * 32 + lk * 8;
    bf16x8 a0 = *reinterpret_cast<const bf16x8*>(qp + (size_t)(i0 + wm + lr) * 64 + k0);
    bf16x8 a1 = *reinterpret_cast<const bf16x8*>(qp + (size_t)(i0 + wm + 16 + lr) * 64 + k0);
    bf16x8 b0 = *reinterpret_cast<const bf16x8*>(kp + (size_t)(j0 + wn + lr) * 64 + k0);
    bf16x8 b1 = *reinterpret_cast<const bf16x8*>(kp + (size_t)(j0 + wn + 16 + lr) * 64 + k0);
    acc[0][0] = MFMA16(a0, b0, acc[0][0]);
    acc[0][1] = MFMA16(a0, b1, acc[0][1]);
    acc[1][0] = MFMA16(a1, b0, acc[1][0]);
    acc[1][1] = MFMA16(a1, b1, acc[1][1]);
  }
#pragma unroll
  for (int mf = 0; mf < 2; ++mf)
#pragma unroll
    for (int nf = 0; nf < 2; ++nf) {
      int j = j0 + wn + nf * 16 + lr;
      float e = endm[b * S + j];
#pragma unroll
      for (int reg = 0; reg < 4; ++reg) {
        int i = i0 + wm + mf * 16 + lk * 4 + reg;
        float g = graph[(size_t)(b * S + i) * S + j];
        float s = acc[mf][nf][reg] * 0.125f + (1.0f - g - e) * (-30000.0f);
        sc[(((size_t)b * S + i) * NH + hh) * S + j] = __float2half(s);
      }
    }
}

// ---------------------------------------------------------------------------
// K4: per (b,i): s = sc[i,h,j] + qr.rel^T; p = exp(min(s,80)); den-reduce;
// probs = p/den (bf16, layout [b,h,i,j]). Register software-pipeline on the
// rel stream (nontemporal), p kept in statically-indexed regs.
// ---------------------------------------------------------------------------
__global__ __launch_bounds__(256) void k_relsm(const short* __restrict__ qrb,
                                               const float* __restrict__ rel,
                                               const __half* __restrict__ sc,
                                               short* __restrict__ probs) {
  __shared__ float den_lds[64];
  const int i = blockIdx.x, b = blockIdx.y;
  const int t = threadIdx.x;
  const int w = t >> 6, lane = t & 63;
  const int lr = lane & 15, fq = lane >> 4;
  const int hA = (lr < NH) ? lr : 0;  // clamp pad A-rows (outputs discarded)
  const short* qrow = qrb + ((size_t)(b * NH + hA) * S + i) * 64;
  bf16x8 a0 = *reinterpret_cast<const bf16x8*>(qrow + fq * 8);
  bf16x8 a1 = *reinterpret_cast<const bf16x8*>(qrow + 32 + fq * 8);
  // per-lane base into this block's rel slab; advances 16 rows (1024 f) per tt
  const float* rp = rel + (((size_t)(b * S) + i) * S + (size_t)(w * 128 + lr)) * 64 + fq * 8;
  const __half* scp = sc + ((size_t)(b * S) + i) * NH * S;  // hot 12KB region
  float p[8][4];
  float den[4] = {0.f, 0.f, 0.f, 0.f};
  f32x4 c0 = ld4nt(rp), c1 = ld4nt(rp + 4), c2 = ld4nt(rp + 32), c3 = ld4nt(rp + 36);
#pragma unroll
  for (int tt = 0; tt < 8; ++tt) {
    f32x4 n0, n1, n2, n3;
    if (tt < 7) {
      const float* rn = rp + (size_t)(tt + 1) * 1024;
      n0 = ld4nt(rn); n1 = ld4nt(rn + 4); n2 = ld4nt(rn + 32); n3 = ld4nt(rn + 36);
    }
    bf16x8 b0 = cvt8(c0, c1), b1 = cvt8(c2, c3);
    f32x4 acc = {};
    acc = MFMA16(a0, b0, acc);
    acc = MFMA16(a1, b1, acc);
    const int j0 = w * 128 + tt * 16;
#pragma unroll
    for (int r = 0; r < 4; ++r) {
      int h = fq * 4 + r;
      float s = acc[r] + __half2float(scp[h * S + j0 + lr]);
      float pe = __expf(fminf(s, 80.0f));
      den[r] += pe;
      p[tt][r] = pe;
    }
    if (tt < 7) { c0 = n0; c1 = n1; c2 = n2; c3 = n3; }
  }
#pragma unroll
  for (int r = 0; r < 4; ++r) {
    float d = den[r];
    d += __shfl_xor(d, 1); d += __shfl_xor(d, 2);
    d += __shfl_xor(d, 4); d += __shfl_xor(d, 8);
    den[r] = d;
  }
  if (lr == 0) {
#pragma unroll
    for (int r = 0; r < 4; ++r) den_lds[w * 16 + fq * 4 + r] = den[r];
  }
  __syncthreads();
  float invd[4];
#pragma unroll
  for (int r = 0; r < 4; ++r) {
    int h = fq * 4 + r;
    invd[r] = 1.0f / (den_lds[h] + den_lds[16 + h] + den_lds[32 + h] + den_lds[48 + h]);
  }
#pragma unroll
  for (int tt = 0; tt < 8; ++tt) {
    int j0 = w * 128 + tt * 16;
#pragma unroll
    for (int r = 0; r < 4; ++r) {
      int h = fq * 4 + r;
      if (h < NH)
        probs[((size_t)(b * NH + h) * S + i) * S + j0 + lr] = f2bf(p[tt][r] * invd[r]);
    }
  }
}

// ---------------------------------------------------------------------------
// K5: ctx = probs @ v via MFMA. Block = 64i x 64d per (b,h); v tile
// LDS-transposed with XOR j-block swizzle (conflict-free b128 reads).
// ---------------------------------------------------------------------------
__global__ __launch_bounds__(256) void k_pv2(const short* __restrict__ probs,
                                             const short* __restrict__ v,
                                             float* __restrict__ out) {
  __shared__ short vt[64 * 72];  // [d][j-local]
  const int i0 = blockIdx.x * 64;
  const int h = blockIdx.y, b = blockIdx.z;
  const short* __restrict__ vp = v + (size_t)((b * NH + h) * S) * HD;
  const short* __restrict__ pp = probs + (size_t)((b * NH + h) * S) * S;
  const int t = threadIdx.x;
  const int w = t >> 6, lane = t & 63;
  const int wm = (w >> 1) * 32, wn = (w & 1) * 32;
  const int lr = lane & 15, lk = lane >> 4;
  f32x4 acc[2][2] = {};
  for (int j0 = 0; j0 < S; j0 += 64) {
    __syncthreads();
#pragma unroll
    for (int it = 0; it < 2; ++it) {
      int jr = it * 32 + (t >> 3), c8 = t & 7;
      bf16x8 vv = *reinterpret_cast<const bf16x8*>(vp + (size_t)(j0 + jr) * 64 + c8 * 8);
      int jsw = (((jr >> 3) ^ c8) << 3) | (jr & 7);
#pragma unroll
      for (int u = 0; u < 8; ++u) vt[(c8 * 8 + u) * 72 + jsw] = vv[u];
    }
    __syncthreads();
#pragma unroll
    for (int ks = 0; ks < 2; ++ks) {
      const short* prow = pp + j0 + ks * 32 + lk * 8;
      bf16x8 a0 = *reinterpret_cast<const bf16x8*>(prow + (size_t)(i0 + wm + lr) * S);
      bf16x8 a1 = *reinterpret_cast<const bf16x8*>(prow + (size_t)(i0 + wm + 16 + lr) * S);
      int r0 = wn + lr, r1 = wn + 16 + lr;
      int jb = ks * 4 + lk;
      bf16x8 b0 = *reinterpret_cast<const bf16x8*>(&vt[r0 * 72 + ((jb ^ ((r0 >> 3) & 7)) << 3)]);
      bf16x8 b1 = *reinterpret_cast<const bf16x8*>(&vt[r1 * 72 + ((jb ^ ((r1 >> 3) & 7)) << 3)]);
      acc[0][0] = MFMA16(a0, b0, acc[0][0]);
      acc[0][1] = MFMA16(a0, b1, acc[0][1]);
      acc[1][0] = MFMA16(a1, b0, acc[1][0]);
      acc[1][1] = MFMA16(a1, b1, acc[1][1]);
    }
  }
#pragma unroll
  for (int mf = 0; mf < 2; ++mf)
#pragma unroll
    for (int nf = 0; nf < 2; ++nf) {
      int d = wn + nf * 16 + lr;
#pragma unroll
      for (int reg = 0; reg < 4; ++reg) {
        int i = i0 + wm + mf * 16 + lk * 4 + reg;
        out[((size_t)(b * S) + i) * HID + h * 64 + d] = acc[mf][nf][reg];
      }
    }
}

// ---------------------------------------------------------------------------
extern "C" void kernel_launch(void* const* d_in, const int* in_sizes, int n_in,
                              void* d_out, int out_size, void* d_ws, size_t ws_size,
                              hipStream_t stream) {
  const float* x     = (const float*)d_in[0];
  const float* graph = (const float*)d_in[1];
  const float* endm  = (const float*)d_in[2];
  const float* rel   = (const float*)d_in[3];
  const float* Wq = (const float*)d_in[4];  const float* bq = (const float*)d_in[5];
  const float* Wk = (const float*)d_in[6];  const float* bk = (const float*)d_in[7];
  const float* Wv = (const float*)d_in[8];  const float* bv = (const float*)d_in[9];
  const float* Wr = (const float*)d_in[10]; // br dropped: softmax-invariant

  short* qb  = (short*)d_ws;
  short* kb  = qb + QKV_N;
  short* vb  = kb + QKV_N;
  short* qrb = vb + QKV_N;
  __half* scores = (__half*)(qrb + QKV_N);          // f16, [b][i][h][j]
  short* probs   = (short*)(scores + SCORES_N);     // bf16, [b][h][i][j]
  const size_t need = (size_t)4 * QKV_N * 2 + SCORES_N * 2 + SCORES_N * 2;
  if (ws_size < need) return;

  k_qkv<<<dim3(32, 36), 256, 0, stream>>>(x, Wq, bq, Wk, bk, Wv, bv, qb);
  k_qr<<<dim3(8, NH, B), 256, 0, stream>>>(qb, Wr, qrb);
  k_qk<<<dim3(8, 8, B * NH), 256, 0, stream>>>(qb, kb, graph, endm, scores);
  k_relsm<<<dim3(S, B), 256, 0, stream>>>(qrb, rel, scores, probs);
  k_pv2<<<dim3(8, NH, B), 256, 0, stream>>>(probs, vb, (float*)d_out);
}